// Round 1
// baseline (1705.704 us; speedup 1.0000x reference)
//
#include <hip/hip_runtime.h>
#include <cmath>

#define B_    8
#define T_    4096
#define D_    256
#define M_    1024
#define L_    4102     // T-1+CTX
#define CTX_  7
#define NROW_ 32768    // B*T

// ---------------- workspace layout (float elements) ----------------
constexpr size_t OFF_DM    = 0;                          // 32768*1024
constexpr size_t OFF_CTXN  = OFF_DM   + (size_t)NROW_ * M_;     // 33,554,432
constexpr size_t OFF_CTXO  = OFF_CTXN + (size_t)B_ * L_ * D_;   // +8,400,896
constexpr size_t OFF_CUR   = OFF_CTXO + (size_t)B_ * D_ * T_;   // +8,388,608
constexpr size_t OFF_CUR2  = OFF_CUR  + (size_t)NROW_ * D_;     // +8,388,608
constexpr size_t OFF_IDX   = OFF_CUR2 + NROW_;                  // +32,768
constexpr size_t OFF_ESQ   = OFF_IDX  + NROW_;                  // +32,768
constexpr size_t OFF_SOFT  = OFF_ESQ  + M_;
constexpr size_t OFF_HIST  = OFF_SOFT + M_;
constexpr size_t OFF_SUMSQ = OFF_HIST + M_;
// total = OFF_SUMSQ + 8 = 58,801,160 floats = ~235 MB

// ---------------- sum of squares per batch (for scale) ----------------
__global__ __launch_bounds__(256) void k_sumsq(const float* __restrict__ x,
                                               float* __restrict__ sumsq) {
  const int b = blockIdx.x >> 6;
  const int chunk = blockIdx.x & 63;
  const float4* xb = (const float4*)(x + (size_t)b * T_ * D_);
  const int N4 = (T_ - 1) * D_ / 4;  // 262080 float4s (first 4095 rows)
  float s = 0.f;
  for (int j = chunk * 256 + threadIdx.x; j < N4; j += 64 * 256) {
    float4 v = xb[j];
    s += v.x * v.x + v.y * v.y + v.z * v.z + v.w * v.w;
  }
  #pragma unroll
  for (int off = 32; off; off >>= 1) s += __shfl_down(s, off, 64);
  __shared__ float red[4];
  const int lane = threadIdx.x & 63, wv = threadIdx.x >> 6;
  if (lane == 0) red[wv] = s;
  __syncthreads();
  if (threadIdx.x == 0) atomicAdd(&sumsq[b], (red[0] + red[1]) + (red[2] + red[3]));
}

// ---------------- build noisy context input, layout [B][L][D] ----------------
__global__ __launch_bounds__(256) void k_noisy(const float* __restrict__ x,
                                               const float* __restrict__ noise,
                                               const int* __restrict__ epo,
                                               const float* __restrict__ sumsq,
                                               float* __restrict__ ctxn) {
  const int b = blockIdx.z;
  const int i0 = blockIdx.y * 32;
  const int t0 = blockIdx.x * 32;
  const int tx = threadIdx.x & 31, ty = threadIdx.x >> 5;
  __shared__ float tile[32][33];
  // read noise[b][i0+r][t0+tx] (coalesced in tau)
  for (int r = ty; r < 32; r += 8) {
    const int tau = t0 + tx;
    tile[r][tx] = (tau < L_) ? noise[((size_t)b * D_ + i0 + r) * L_ + tau] : 0.f;
  }
  __syncthreads();
  const float scale = sqrtf(sumsq[b] / (float)(D_ * L_));
  const float coef = 0.5f * powf(0.5f, (float)epo[0] / 10.0f) * scale;
  for (int r = ty; r < 32; r += 8) {
    const int tau = t0 + r;
    if (tau >= L_) continue;
    const int i = i0 + tx;
    float v = coef * tile[tx][r];
    if (tau >= CTX_) v += x[((size_t)b * T_ + (tau - CTX_)) * D_ + i];
    ctxn[((size_t)b * L_ + tau) * D_ + i] = v;   // coalesced in i
  }
}

// ---------------- 7-tap conv as tiled matmul: out[B][O][T] ----------------
__global__ __launch_bounds__(256) void k_conv(const float* __restrict__ in,   // [B][L][D]
                                              const float* __restrict__ w,    // [O][I][7]
                                              float* __restrict__ out) {      // [B][O][T]
  const int t0 = blockIdx.x * 128;
  const int o0 = blockIdx.y * 128;
  const int b  = blockIdx.z;
  const int tid = threadIdx.x;
  const int col = tid & 15;     // t fragment
  const int rowt = tid >> 4;    // o fragment
  __shared__ float wS[56 * 129];    // [k=i*7+h][o] padded
  __shared__ float inS[8 * 136];    // [i][tau] padded
  float acc[8][8] = {};
  for (int ic = 0; ic < 32; ++ic) {
    __syncthreads();
    for (int j = tid; j < 7168; j += 256) {
      const int o = j / 56, kk = j % 56;          // kk fastest over lanes -> coalesced
      wS[kk * 129 + o] = w[(size_t)(o0 + o) * 1792 + ic * 56 + kk];
    }
    for (int j = tid; j < 1072; j += 256) {       // 134 taus x 8 i
      const int tau = j >> 3, i = j & 7;
      inS[i * 136 + tau] = in[((size_t)b * L_ + t0 + tau) * D_ + ic * 8 + i];
    }
    __syncthreads();
    #pragma unroll 1
    for (int i = 0; i < 8; ++i) {
      #pragma unroll
      for (int h = 0; h < 7; ++h) {
        float wv[8], iv[8];
        #pragma unroll
        for (int oo = 0; oo < 8; ++oo) wv[oo] = wS[(i * 7 + h) * 129 + rowt + 16 * oo];
        #pragma unroll
        for (int tt = 0; tt < 8; ++tt) iv[tt] = inS[i * 136 + col + 16 * tt + h];
        #pragma unroll
        for (int oo = 0; oo < 8; ++oo)
          #pragma unroll
          for (int tt = 0; tt < 8; ++tt)
            acc[oo][tt] = fmaf(wv[oo], iv[tt], acc[oo][tt]);
      }
    }
  }
  #pragma unroll
  for (int oo = 0; oo < 8; ++oo) {
    const size_t ob = ((size_t)b * D_ + o0 + rowt + 16 * oo) * T_;
    #pragma unroll
    for (int tt = 0; tt < 8; ++tt)
      out[ob + t0 + col + 16 * tt] = acc[oo][tt];
  }
}

// ---------------- row L2-norms (256-wide rows): one wave per row ----------------
__global__ __launch_bounds__(256) void k_rownorm(const float* __restrict__ a,
                                                 float* __restrict__ out) {
  const int row = (blockIdx.x << 2) + (threadIdx.x >> 6);
  const int lane = threadIdx.x & 63;
  const float4 v = ((const float4*)a)[((size_t)row << 6) + lane];
  float s = v.x * v.x + v.y * v.y + v.z * v.z + v.w * v.w;
  #pragma unroll
  for (int off = 32; off; off >>= 1) s += __shfl_down(s, off, 64);
  if (lane == 0) out[row] = s;
}

// ---------------- fuse1: cur[row][o] = prelu(w_f1 @ [x; ctx_out]) ----------------
__global__ __launch_bounds__(256) void k_fuse1(const float* __restrict__ x,
                                               const float* __restrict__ ctxo,
                                               const float* __restrict__ wf,
                                               const float* __restrict__ a1,
                                               float* __restrict__ cur) {
  const int rt = blockIdx.x;            // 0..255 row tiles
  const int o0 = blockIdx.y << 7;       // 0 or 128
  const int b = rt >> 5;
  const int t0 = (rt & 31) << 7;
  const int tid = threadIdx.x, col = tid & 15, rowt = tid >> 4;
  __shared__ float sA[16 * 130];        // [c][t]  (t side -> rowt)
  __shared__ float sB[16 * 130];        // [c][o]  (o side -> col)
  float acc[8][8] = {};
  for (int cc = 0; cc < 512; cc += 16) {
    __syncthreads();
    if (cc < 256) {
      for (int j = tid; j < 2048; j += 256) {
        const int t = j >> 4, c = j & 15;
        sA[c * 130 + t] = x[((size_t)(b * T_ + t0 + t)) * D_ + cc + c];
      }
    } else {
      for (int j = tid; j < 2048; j += 256) {
        const int c = j >> 7, t = j & 127;
        sA[c * 130 + t] = ctxo[((size_t)b * D_ + (cc - 256 + c)) * T_ + t0 + t];
      }
    }
    for (int j = tid; j < 2048; j += 256) {
      const int o = j >> 4, c = j & 15;
      sB[c * 130 + o] = wf[(size_t)(o0 + o) * 512 + cc + c];
    }
    __syncthreads();
    #pragma unroll 4
    for (int c = 0; c < 16; ++c) {
      float av[8], bv[8];
      #pragma unroll
      for (int k = 0; k < 8; ++k) av[k] = sA[c * 130 + rowt + 16 * k];
      #pragma unroll
      for (int k = 0; k < 8; ++k) bv[k] = sB[c * 130 + col + 16 * k];
      #pragma unroll
      for (int i = 0; i < 8; ++i)
        #pragma unroll
        for (int j2 = 0; j2 < 8; ++j2)
          acc[i][j2] = fmaf(av[i], bv[j2], acc[i][j2]);
    }
  }
  const float alpha = a1[0];
  #pragma unroll
  for (int i = 0; i < 8; ++i) {
    const int t = t0 + rowt + 16 * i;
    #pragma unroll
    for (int j2 = 0; j2 < 8; ++j2) {
      const int o = o0 + col + 16 * j2;
      float v = acc[i][j2];
      v = (v >= 0.f) ? v : alpha * v;
      cur[((size_t)(b * T_ + t)) * D_ + o] = v;   // coalesced in o
    }
  }
}

// ---------------- dist matmul: dm[row][m] = -(|cur|^2 + |e|^2 - 2 cur.e) ----------------
__global__ __launch_bounds__(256) void k_dist(const float* __restrict__ cur,
                                              const float* __restrict__ E,
                                              const float* __restrict__ cur2,
                                              const float* __restrict__ esq,
                                              float* __restrict__ dm) {
  const int m0 = blockIdx.x << 7;   // 0..7 tiles of m
  const int r0 = blockIdx.y << 7;   // 0..255 tiles of rows
  const int tid = threadIdx.x, col = tid & 15, rowt = tid >> 4;
  __shared__ float sA[16 * 130];    // [c][row]
  __shared__ float sB[16 * 130];    // [c][m]
  float acc[8][8] = {};
  for (int cc = 0; cc < 256; cc += 16) {
    __syncthreads();
    for (int j = tid; j < 2048; j += 256) {
      const int rr = j >> 4, c = j & 15;
      sA[c * 130 + rr] = cur[((size_t)(r0 + rr)) * D_ + cc + c];
    }
    for (int j = tid; j < 2048; j += 256) {
      const int mm = j >> 4, c = j & 15;
      sB[c * 130 + mm] = E[((size_t)(m0 + mm)) * D_ + cc + c];
    }
    __syncthreads();
    #pragma unroll 4
    for (int c = 0; c < 16; ++c) {
      float av[8], bv[8];
      #pragma unroll
      for (int k = 0; k < 8; ++k) av[k] = sA[c * 130 + rowt + 16 * k];
      #pragma unroll
      for (int k = 0; k < 8; ++k) bv[k] = sB[c * 130 + col + 16 * k];
      #pragma unroll
      for (int i = 0; i < 8; ++i)
        #pragma unroll
        for (int j2 = 0; j2 < 8; ++j2)
          acc[i][j2] = fmaf(av[i], bv[j2], acc[i][j2]);
    }
  }
  float c2[8], eq[8];
  #pragma unroll
  for (int i = 0; i < 8; ++i) c2[i] = cur2[r0 + rowt + 16 * i];
  #pragma unroll
  for (int j2 = 0; j2 < 8; ++j2) eq[j2] = esq[m0 + col + 16 * j2];
  #pragma unroll
  for (int i = 0; i < 8; ++i) {
    const size_t rb = (size_t)(r0 + rowt + 16 * i) * M_;
    #pragma unroll
    for (int j2 = 0; j2 < 8; ++j2) {
      const float dist = c2[i] + eq[j2] - 2.0f * acc[i][j2];
      dm[rb + m0 + col + 16 * j2] = -dist;       // coalesced in m
    }
  }
}

// ---------------- per-row: softmax accumulation, hard argmax, gumbel argmax ----------------
__global__ __launch_bounds__(256) void k_soft(const float* __restrict__ dm,
                                              const float* __restrict__ gu,
                                              float* __restrict__ soft_sums,
                                              unsigned* __restrict__ hist,
                                              int* __restrict__ idx_out,
                                              float* __restrict__ idxf_out) {
  const int tid = threadIdx.x;
  const int lane = tid & 63, wv = tid >> 6;
  __shared__ float accS[1024];
  __shared__ float redF[4];
  __shared__ int redI[4];
  for (int j = tid; j < 1024; j += 256) accS[j] = 0.f;
  __syncthreads();
  for (int rr = 0; rr < 128; ++rr) {
    const int r = (blockIdx.x << 7) + rr;
    const float4 d4 = ((const float4*)dm)[((size_t)r << 8) + tid];
    // 1) row max
    float mx = fmaxf(fmaxf(d4.x, d4.y), fmaxf(d4.z, d4.w));
    #pragma unroll
    for (int off = 32; off; off >>= 1) mx = fmaxf(mx, __shfl_down(mx, off, 64));
    __syncthreads();
    if (lane == 0) redF[wv] = mx;
    __syncthreads();
    mx = fmaxf(fmaxf(redF[0], redF[1]), fmaxf(redF[2], redF[3]));
    // 2) exp + sum
    const float e0 = expf(d4.x - mx), e1 = expf(d4.y - mx);
    const float e2 = expf(d4.z - mx), e3 = expf(d4.w - mx);
    float s = (e0 + e1) + (e2 + e3);
    #pragma unroll
    for (int off = 32; off; off >>= 1) s += __shfl_down(s, off, 64);
    __syncthreads();
    if (lane == 0) redF[wv] = s;
    __syncthreads();
    const float inv = 1.0f / ((redF[0] + redF[1]) + (redF[2] + redF[3]));
    accS[(tid << 2) + 0] += e0 * inv;
    accS[(tid << 2) + 1] += e1 * inv;
    accS[(tid << 2) + 2] += e2 * inv;
    accS[(tid << 2) + 3] += e3 * inv;
    // 3) hard argmax(dm), first-occurrence semantics
    float bv = d4.x; int bi = (tid << 2);
    if (d4.y > bv) { bv = d4.y; bi = (tid << 2) + 1; }
    if (d4.z > bv) { bv = d4.z; bi = (tid << 2) + 2; }
    if (d4.w > bv) { bv = d4.w; bi = (tid << 2) + 3; }
    #pragma unroll
    for (int off = 32; off; off >>= 1) {
      const float v2 = __shfl_down(bv, off, 64);
      const int i2 = __shfl_down(bi, off, 64);
      if (v2 > bv || (v2 == bv && i2 < bi)) { bv = v2; bi = i2; }
    }
    __syncthreads();
    if (lane == 0) { redF[wv] = bv; redI[wv] = bi; }
    __syncthreads();
    if (tid == 0) {
      float cv = redF[0]; int ci = redI[0];
      #pragma unroll
      for (int w2 = 1; w2 < 4; ++w2)
        if (redF[w2] > cv || (redF[w2] == cv && redI[w2] < ci)) { cv = redF[w2]; ci = redI[w2]; }
      atomicAdd(&hist[ci], 1u);
    }
    // 4) gumbel argmax(dm + g)
    const float4 u4 = ((const float4*)gu)[((size_t)r << 8) + tid];
    const float z0 = d4.x - logf(-logf(fminf(fmaxf(u4.x, 1e-10f), 1.0f - 1e-7f)));
    const float z1 = d4.y - logf(-logf(fminf(fmaxf(u4.y, 1e-10f), 1.0f - 1e-7f)));
    const float z2 = d4.z - logf(-logf(fminf(fmaxf(u4.z, 1e-10f), 1.0f - 1e-7f)));
    const float z3 = d4.w - logf(-logf(fminf(fmaxf(u4.w, 1e-10f), 1.0f - 1e-7f)));
    bv = z0; bi = (tid << 2);
    if (z1 > bv) { bv = z1; bi = (tid << 2) + 1; }
    if (z2 > bv) { bv = z2; bi = (tid << 2) + 2; }
    if (z3 > bv) { bv = z3; bi = (tid << 2) + 3; }
    #pragma unroll
    for (int off = 32; off; off >>= 1) {
      const float v2 = __shfl_down(bv, off, 64);
      const int i2 = __shfl_down(bi, off, 64);
      if (v2 > bv || (v2 == bv && i2 < bi)) { bv = v2; bi = i2; }
    }
    __syncthreads();
    if (lane == 0) { redF[wv] = bv; redI[wv] = bi; }
    __syncthreads();
    if (tid == 0) {
      float cv = redF[0]; int ci = redI[0];
      #pragma unroll
      for (int w2 = 1; w2 < 4; ++w2)
        if (redF[w2] > cv || (redF[w2] == cv && redI[w2] < ci)) { cv = redF[w2]; ci = redI[w2]; }
      idx_out[r] = ci;
      idxf_out[r] = (float)ci;
    }
  }
  __syncthreads();
  for (int j = tid; j < 1024; j += 256) atomicAdd(&soft_sums[j], accS[j]);
}

// ---------------- perplexities ----------------
__global__ __launch_bounds__(256) void k_perp(const float* __restrict__ soft,
                                              const unsigned* __restrict__ hist,
                                              float* __restrict__ out2) {
  const int tid = threadIdx.x;
  float cp = 0.f, pp = 0.f;
  for (int m = tid; m < 1024; m += 256) {
    const float hp = (float)hist[m] * (1.0f / 32768.0f);
    cp += hp * log2f(hp + 1e-10f);
    const float q = soft[m] * (1.0f / 32768.0f);
    pp += q * log2f(q + 1e-10f);
  }
  #pragma unroll
  for (int off = 32; off; off >>= 1) {
    cp += __shfl_down(cp, off, 64);
    pp += __shfl_down(pp, off, 64);
  }
  __shared__ float rc[4], rp[4];
  const int lane = tid & 63, wv = tid >> 6;
  if (lane == 0) { rc[wv] = cp; rp[wv] = pp; }
  __syncthreads();
  if (tid == 0) {
    out2[0] = -((rc[0] + rc[1]) + (rc[2] + rc[3]));
    out2[1] = -((rp[0] + rp[1]) + (rp[2] + rp[3]));
  }
}

// ---------------- fuse2: quantized[b][t][o] = prelu(w_f2 @ [E[idx]; ctx_out]) ----------------
__global__ __launch_bounds__(256) void k_fuse2(const int* __restrict__ idx,
                                               const float* __restrict__ E,
                                               const float* __restrict__ ctxo,
                                               const float* __restrict__ wf,
                                               const float* __restrict__ a2,
                                               float* __restrict__ outq) {
  const int rt = blockIdx.x;
  const int o0 = blockIdx.y << 7;
  const int b = rt >> 5;
  const int t0 = (rt & 31) << 7;
  const int tid = threadIdx.x, col = tid & 15, rowt = tid >> 4;
  __shared__ float sA[16 * 130];
  __shared__ float sB[16 * 130];
  __shared__ int idxS[128];
  if (tid < 128) idxS[tid] = idx[b * T_ + t0 + tid];
  float acc[8][8] = {};
  for (int cc = 0; cc < 512; cc += 16) {
    __syncthreads();
    if (cc < 256) {
      for (int j = tid; j < 2048; j += 256) {
        const int t = j >> 4, c = j & 15;
        sA[c * 130 + t] = E[(size_t)idxS[t] * D_ + cc + c];
      }
    } else {
      for (int j = tid; j < 2048; j += 256) {
        const int c = j >> 7, t = j & 127;
        sA[c * 130 + t] = ctxo[((size_t)b * D_ + (cc - 256 + c)) * T_ + t0 + t];
      }
    }
    for (int j = tid; j < 2048; j += 256) {
      const int o = j >> 4, c = j & 15;
      sB[c * 130 + o] = wf[(size_t)(o0 + o) * 512 + cc + c];
    }
    __syncthreads();
    #pragma unroll 4
    for (int c = 0; c < 16; ++c) {
      float av[8], bv[8];
      #pragma unroll
      for (int k = 0; k < 8; ++k) av[k] = sA[c * 130 + rowt + 16 * k];
      #pragma unroll
      for (int k = 0; k < 8; ++k) bv[k] = sB[c * 130 + col + 16 * k];
      #pragma unroll
      for (int i = 0; i < 8; ++i)
        #pragma unroll
        for (int j2 = 0; j2 < 8; ++j2)
          acc[i][j2] = fmaf(av[i], bv[j2], acc[i][j2]);
    }
  }
  const float alpha = a2[0];
  #pragma unroll
  for (int i = 0; i < 8; ++i) {
    const int t = t0 + rowt + 16 * i;
    #pragma unroll
    for (int j2 = 0; j2 < 8; ++j2) {
      const int o = o0 + col + 16 * j2;
      float v = acc[i][j2];
      v = (v >= 0.f) ? v : alpha * v;
      outq[((size_t)(b * T_ + t)) * D_ + o] = v;
    }
  }
}

extern "C" void kernel_launch(void* const* d_in, const int* in_sizes, int n_in,
                              void* d_out, int out_size, void* d_ws, size_t ws_size,
                              hipStream_t stream) {
  (void)in_sizes; (void)n_in; (void)out_size; (void)ws_size;
  const float* x     = (const float*)d_in[0];
  const float* noise = (const float*)d_in[1];
  const float* gu    = (const float*)d_in[2];
  const int*   epo   = (const int*)d_in[3];
  const float* emb   = (const float*)d_in[4];
  const float* wctx  = (const float*)d_in[5];
  const float* wf1   = (const float*)d_in[6];
  const float* a1    = (const float*)d_in[7];
  const float* wf2   = (const float*)d_in[8];
  const float* a2    = (const float*)d_in[9];

  float* ws   = (float*)d_ws;
  float* dm   = ws + OFF_DM;
  float* ctxn = ws + OFF_CTXN;
  float* ctxo = ws + OFF_CTXO;
  float* cur  = ws + OFF_CUR;
  float* cur2 = ws + OFF_CUR2;
  int*   idxi = (int*)(ws + OFF_IDX);
  float* esq  = ws + OFF_ESQ;
  float* soft = ws + OFF_SOFT;
  unsigned* hist = (unsigned*)(ws + OFF_HIST);
  float* sumsq = ws + OFF_SUMSQ;

  float* outq = (float*)d_out;
  float* scal = outq + (size_t)NROW_ * D_;      // [cp, pp]
  float* idxf = scal + 2;                        // 32768 indices as float

  // zero soft/hist/sumsq (contiguous: OFF_SOFT..OFF_SUMSQ+8)
  hipMemsetAsync(ws + OFF_SOFT, 0, (M_ + M_ + 8) * sizeof(float), stream);

  k_sumsq <<<512, 256, 0, stream>>>(x, sumsq);
  k_noisy <<<dim3(129, 8, 8), 256, 0, stream>>>(x, noise, epo, sumsq, ctxn);
  k_conv  <<<dim3(32, 2, 8), 256, 0, stream>>>(ctxn, wctx, ctxo);
  k_rownorm<<<M_ / 4, 256, 0, stream>>>(emb, esq);
  k_fuse1 <<<dim3(256, 2), 256, 0, stream>>>(x, ctxo, wf1, a1, cur);
  k_rownorm<<<NROW_ / 4, 256, 0, stream>>>(cur, cur2);
  k_dist  <<<dim3(8, 256), 256, 0, stream>>>(cur, emb, cur2, esq, dm);
  k_soft  <<<256, 256, 0, stream>>>(dm, gu, soft, hist, idxi, idxf);
  k_perp  <<<1, 256, 0, stream>>>(soft, hist, scal);
  k_fuse2 <<<dim3(256, 2), 256, 0, stream>>>(idxi, emb, ctxo, wf2, a2, outq);
}

// Round 2
// 1131.569 us; speedup vs baseline: 1.5074x; 1.5074x over previous
//
#include <hip/hip_runtime.h>
#include <cmath>

#define B_    8
#define T_    4096
#define D_    256
#define M_    1024
#define L_    4102     // T-1+CTX
#define LP_   4104     // padded stride for ctxn rows (16B-aligned float4 rows)
#define CTX_  7
#define NROW_ 32768    // B*T

// ---------------- workspace layout (float elements) ----------------
// DM (33.5M) overlaps XT (8.39M): XT is dead before k_dist writes DM.
// CURT overlaps CTXN: CTXN dead after k_conv, CURT written by k_fuse1.
constexpr size_t OFF_DM    = 0;                                  // 33,554,432 (XT = first 8,388,608)
constexpr size_t OFF_XT    = 0;
constexpr size_t OFF_CTXN  = 33554432;                           // 8*256*4104 = 8,404,992
constexpr size_t OFF_CURT  = 33554432;                           // [256][32768] = 8,388,608
constexpr size_t OFF_CTXO  = OFF_CTXN + (size_t)B_ * D_ * LP_;   // 41,959,424 ; [b][o][t] 8,388,608
constexpr size_t OFF_CUR2  = OFF_CTXO + (size_t)B_ * D_ * T_;    // 50,348,032 ; 32768
constexpr size_t OFF_SOFT  = OFF_CUR2 + NROW_;                   // 4096 (4 replicas)
constexpr size_t OFF_HIST  = OFF_SOFT + 4096;                    // 1024
constexpr size_t OFF_SUMSQ = OFF_HIST + 1024;                    // 16 (8 + pad)
constexpr size_t OFF_ESQ   = OFF_SUMSQ + 16;                     // 1024
constexpr size_t OFF_IDX   = OFF_ESQ + 1024;                     // 32768 ints
constexpr size_t OFF_ET    = OFF_IDX + NROW_;                    // [256][1024] 262,144
constexpr size_t OFF_W1T   = OFF_ET + 262144;                    // [512][256] 131,072
constexpr size_t OFF_W2T   = OFF_W1T + 131072;                   // [512][256] 131,072
constexpr size_t OFF_WCT   = OFF_W2T + 131072;                   // [1792][256] 458,752
constexpr size_t OFF_P     = OFF_WCT + 458752;                   // [1024][256] 262,144
// end ~51.66M floats = 207 MB

// ---------------- generic 32x32 transpose: src[R][C] -> dst[C][R] ----------------
__global__ __launch_bounds__(256) void k_transpose(const float* __restrict__ src,
                                                   float* __restrict__ dst,
                                                   int R, int C) {
  const int c0 = blockIdx.x << 5, r0 = blockIdx.y << 5;
  const int tx = threadIdx.x & 31, ty = threadIdx.x >> 5;
  __shared__ float tile[32][33];
  for (int rr = ty; rr < 32; rr += 8) {
    const int r = r0 + rr, c = c0 + tx;
    tile[rr][tx] = (r < R && c < C) ? src[(size_t)r * C + c] : 0.f;
  }
  __syncthreads();
  for (int rr = ty; rr < 32; rr += 8) {
    const int c = c0 + rr, r = r0 + tx;
    if (c < C && r < R) dst[(size_t)c * R + r] = tile[tx][rr];
  }
}

// ---------------- sum of squares per batch (for scale) ----------------
__global__ __launch_bounds__(256) void k_sumsq(const float* __restrict__ x,
                                               float* __restrict__ sumsq) {
  const int b = blockIdx.x >> 6;
  const int chunk = blockIdx.x & 63;
  const float4* xb = (const float4*)(x + (size_t)b * T_ * D_);
  const int N4 = (T_ - 1) * D_ / 4;
  float s = 0.f;
  for (int j = chunk * 256 + threadIdx.x; j < N4; j += 64 * 256) {
    float4 v = xb[j];
    s += v.x * v.x + v.y * v.y + v.z * v.z + v.w * v.w;
  }
  #pragma unroll
  for (int off = 32; off; off >>= 1) s += __shfl_down(s, off, 64);
  __shared__ float red[4];
  const int lane = threadIdx.x & 63, wv = threadIdx.x >> 6;
  if (lane == 0) red[wv] = s;
  __syncthreads();
  if (threadIdx.x == 0) atomicAdd(&sumsq[b], (red[0] + red[1]) + (red[2] + red[3]));
}

// ---------------- row L2-norms of emb (1024 rows x 256) ----------------
__global__ __launch_bounds__(256) void k_rownorm(const float* __restrict__ a,
                                                 float* __restrict__ out) {
  const int row = (blockIdx.x << 2) + (threadIdx.x >> 6);
  const int lane = threadIdx.x & 63;
  const float4 v = ((const float4*)a)[((size_t)row << 6) + lane];
  float s = v.x * v.x + v.y * v.y + v.z * v.z + v.w * v.w;
  #pragma unroll
  for (int off = 32; off; off >>= 1) s += __shfl_down(s, off, 64);
  if (lane == 0) out[row] = s;
}

// ---------------- noisy ctx input [b][i][tau] (stride LP_) + xT [b][i][t] ----------------
__global__ __launch_bounds__(256) void k_noisy(const float* __restrict__ x,
                                               const float* __restrict__ noise,
                                               const int* __restrict__ epo,
                                               const float* __restrict__ sumsq,
                                               float* __restrict__ ctxn,
                                               float* __restrict__ xT) {
  const int b = blockIdx.z;
  const int i0 = blockIdx.y << 5;
  const int tau0 = blockIdx.x << 5;
  const int tx = threadIdx.x & 31, ty = threadIdx.x >> 5;
  __shared__ float xt[32][33];
  const int tr0 = tau0 - CTX_;
  for (int r = ty; r < 32; r += 8) {
    const int t = tr0 + r;
    xt[r][tx] = (t >= 0 && t < T_) ? x[((size_t)b * T_ + t) * D_ + i0 + tx] : 0.f;
  }
  __syncthreads();
  const float scale = sqrtf(sumsq[b] * (1.0f / (256.0f * 4102.0f)));
  const float coef = 0.5f * powf(0.5f, (float)epo[0] * 0.1f) * scale;
  for (int r = ty; r < 32; r += 8) {
    const int i = i0 + r;
    const int tau = tau0 + tx;
    const float xv = xt[tx][r];   // x[b][tau-7][i] (0 if t OOB)
    if (tau < L_) {
      float v = coef * noise[((size_t)b * D_ + i) * L_ + tau];
      if (tau >= CTX_) v += xv;
      ctxn[((size_t)b * D_ + i) * LP_ + tau] = v;
    }
    if (tau >= CTX_ && tau < T_ + CTX_) {
      xT[((size_t)b * D_ + i) * T_ + (tau - CTX_)] = xv;
    }
  }
}

// ---------------- shared GEMM helpers ----------------
__device__ __forceinline__ void stage16x128(float* __restrict__ dst,
                                            const float* __restrict__ src,
                                            const int gstride, const int tid) {
  #pragma unroll
  for (int p = 0; p < 2; ++p) {
    const int q = p * 256 + tid;            // 0..511 float4s (16 rows x 32)
    const int r = q >> 5, c = (q & 31) << 2;
    *(float4*)&dst[(r << 7) + c] = *(const float4*)&src[(size_t)r * gstride + c];
  }
}

__device__ __forceinline__ void gemm16(const float* __restrict__ sA,
                                       const float* __restrict__ sB,
                                       const int ay, const int bx,
                                       float acc[8][8]) {
  #pragma unroll 4
  for (int c = 0; c < 16; ++c) {
    const float4 a0 = *(const float4*)&sA[(c << 7) + ay];
    const float4 a1 = *(const float4*)&sA[(c << 7) + ay + 4];
    const float4 b0 = *(const float4*)&sB[(c << 7) + bx];
    const float4 b1 = *(const float4*)&sB[(c << 7) + bx + 4];
    const float av[8] = {a0.x, a0.y, a0.z, a0.w, a1.x, a1.y, a1.z, a1.w};
    const float bv[8] = {b0.x, b0.y, b0.z, b0.w, b1.x, b1.y, b1.z, b1.w};
    #pragma unroll
    for (int i = 0; i < 8; ++i)
      #pragma unroll
      for (int j = 0; j < 8; ++j)
        acc[i][j] = fmaf(av[i], bv[j], acc[i][j]);
  }
}

// ---------------- conv: ctxo[b][o][t] = sum_{i,h} WCT[i*7+h][o] * ctxn[b][i][t+h] ----------------
__global__ __launch_bounds__(256) void k_conv(const float* __restrict__ wct,
                                              const float* __restrict__ ctxn,
                                              float* __restrict__ ctxo) {
  const int t0 = blockIdx.x << 7;
  const int o0 = blockIdx.y << 7;
  const int b  = blockIdx.z;
  const int tid = threadIdx.x;
  const int tx = tid & 15, ty = tid >> 4;
  const int bx = tx << 3, ay = ty << 3;   // t-frag, o-frag
  __shared__ float wS[56 * 128];          // [i*7+h][o]
  __shared__ float inS[8 * 136];          // [i][tau] (136 taus staged, 134 used)
  float acc[8][8] = {};                   // [oo][tt]
  for (int ic = 0; ic < 32; ++ic) {
    __syncthreads();
    #pragma unroll
    for (int p = 0; p < 7; ++p) {
      const int q = p * 256 + tid;        // 0..1791 f4s = 56 rows x 32
      const int r = q >> 5, c = (q & 31) << 2;
      *(float4*)&wS[(r << 7) + c] = *(const float4*)&wct[(size_t)(ic * 56 + r) * 256 + o0 + c];
    }
    {
      const int r = tid / 34, c = (tid % 34) << 2;      // 272 f4s = 8 rows x 34
      if (tid < 272)
        *(float4*)&inS[r * 136 + c] = *(const float4*)&ctxn[((size_t)b * D_ + ic * 8 + r) * LP_ + t0 + c];
      if (tid < 16) {
        const int q2 = 256 + tid;
        const int r2 = q2 / 34, c2 = (q2 % 34) << 2;
        *(float4*)&inS[r2 * 136 + c2] = *(const float4*)&ctxn[((size_t)b * D_ + ic * 8 + r2) * LP_ + t0 + c2];
      }
    }
    __syncthreads();
    #pragma unroll 1
    for (int i = 0; i < 8; ++i) {
      float iv[16];
      #pragma unroll
      for (int q = 0; q < 4; ++q)
        *(float4*)&iv[q << 2] = *(const float4*)&inS[i * 136 + bx + (q << 2)];
      #pragma unroll
      for (int h = 0; h < 7; ++h) {
        float wv[8];
        *(float4*)&wv[0] = *(const float4*)&wS[(i * 7 + h) * 128 + ay];
        *(float4*)&wv[4] = *(const float4*)&wS[(i * 7 + h) * 128 + ay + 4];
        #pragma unroll
        for (int oo = 0; oo < 8; ++oo)
          #pragma unroll
          for (int tt = 0; tt < 8; ++tt)
            acc[oo][tt] = fmaf(wv[oo], iv[h + tt], acc[oo][tt]);
      }
    }
  }
  #pragma unroll
  for (int oo = 0; oo < 8; ++oo) {
    float4 v0 = {acc[oo][0], acc[oo][1], acc[oo][2], acc[oo][3]};
    float4 v1 = {acc[oo][4], acc[oo][5], acc[oo][6], acc[oo][7]};
    float* dst = ctxo + ((size_t)b * D_ + o0 + ay + oo) * T_ + t0 + bx;
    *(float4*)dst = v0; *(float4*)(dst + 4) = v1;
  }
}

// ---------------- fuse1 -> curT[o][row] + cur2[row] ----------------
__global__ __launch_bounds__(256) void k_fuse1(const float* __restrict__ xT,
                                               const float* __restrict__ ctxo,
                                               const float* __restrict__ w1T,
                                               const float* __restrict__ a1,
                                               float* __restrict__ curT,
                                               float* __restrict__ cur2) {
  const int bk = blockIdx.x;            // b*32 + ttile
  const int b = bk >> 5;
  const int t0 = (bk & 31) << 7;
  const int o0 = blockIdx.y << 7;
  const int tid = threadIdx.x;
  const int tx = tid & 15, ty = tid >> 4;
  const int ox = ty << 3, tp = tx << 3;  // o-frag (A), t-frag (B)
  __shared__ float smem[4096];
  float* sW = smem;          // [c][o]
  float* sX = smem + 2048;   // [c][t]
  float acc[8][8] = {};      // [oo][tt]
  for (int cc = 0; cc < 512; cc += 16) {
    __syncthreads();
    stage16x128(sW, w1T + (size_t)cc * 256 + o0, 256, tid);
    const float* xsrc = (cc < 256)
        ? xT + ((size_t)b * D_ + cc) * T_ + t0
        : ctxo + ((size_t)b * D_ + (cc - 256)) * T_ + t0;
    stage16x128(sX, xsrc, T_, tid);
    __syncthreads();
    gemm16(sW, sX, ox, tp, acc);
  }
  const float alpha = a1[0];
  const size_t row0 = (size_t)b * T_ + t0;
  float part[8] = {};
  #pragma unroll
  for (int oo = 0; oo < 8; ++oo) {
    #pragma unroll
    for (int tt = 0; tt < 8; ++tt) {
      float v = acc[oo][tt];
      v = (v >= 0.f) ? v : alpha * v;
      acc[oo][tt] = v;
      part[tt] = fmaf(v, v, part[tt]);
    }
    float4 v0 = {acc[oo][0], acc[oo][1], acc[oo][2], acc[oo][3]};
    float4 v1 = {acc[oo][4], acc[oo][5], acc[oo][6], acc[oo][7]};
    float* dst = curT + (size_t)(o0 + ox + oo) * NROW_ + row0 + tp;
    *(float4*)dst = v0; *(float4*)(dst + 4) = v1;
  }
  __syncthreads();
  float* red = smem;   // [128][17]
  #pragma unroll
  for (int tt = 0; tt < 8; ++tt) red[(tp + tt) * 17 + ty] = part[tt];
  __syncthreads();
  if (tid < 128) {
    float s = 0.f;
    #pragma unroll
    for (int k = 0; k < 16; ++k) s += red[tid * 17 + k];
    atomicAdd(&cur2[row0 + tid], s);
  }
}

// ---------------- P[m][o] = sum_c E[m][c] * wf2[o][c]  (c<256 half) ----------------
__global__ __launch_bounds__(256) void k_pmm(const float* __restrict__ ET,
                                             const float* __restrict__ w2T,
                                             float* __restrict__ P) {
  const int m0 = blockIdx.x << 7;
  const int o0 = blockIdx.y << 7;
  const int tid = threadIdx.x;
  const int tx = tid & 15, ty = tid >> 4;
  const int my = ty << 3, ox = tx << 3;
  __shared__ float smem[4096];
  float* sM = smem;
  float* sW = smem + 2048;
  float acc[8][8] = {};   // [mm][oo]
  for (int cc = 0; cc < 256; cc += 16) {
    __syncthreads();
    stage16x128(sM, ET + (size_t)cc * M_ + m0, M_, tid);
    stage16x128(sW, w2T + (size_t)cc * 256 + o0, 256, tid);
    __syncthreads();
    gemm16(sM, sW, my, ox, acc);
  }
  #pragma unroll
  for (int mm = 0; mm < 8; ++mm) {
    float4 v0 = {acc[mm][0], acc[mm][1], acc[mm][2], acc[mm][3]};
    float4 v1 = {acc[mm][4], acc[mm][5], acc[mm][6], acc[mm][7]};
    float* dst = P + (size_t)(m0 + my + mm) * 256 + o0 + ox;
    *(float4*)dst = v0; *(float4*)(dst + 4) = v1;
  }
}

// ---------------- dist: dm[row][m] = -(c2 + e2 - 2*cur.e) ----------------
__global__ __launch_bounds__(256) void k_dist(const float* __restrict__ curT,
                                              const float* __restrict__ ET,
                                              const float* __restrict__ cur2,
                                              const float* __restrict__ esq,
                                              float* __restrict__ dm) {
  const int r0 = blockIdx.x << 7;
  const int m0 = blockIdx.y << 7;
  const int tid = threadIdx.x;
  const int tx = tid & 15, ty = tid >> 4;
  const int ry = ty << 3, mx = tx << 3;
  __shared__ float smem[4096];
  float* sC = smem;
  float* sE = smem + 2048;
  float acc[8][8] = {};   // [rr][mm]
  for (int cc = 0; cc < 256; cc += 16) {
    __syncthreads();
    stage16x128(sC, curT + (size_t)cc * NROW_ + r0, NROW_, tid);
    stage16x128(sE, ET + (size_t)cc * M_ + m0, M_, tid);
    __syncthreads();
    gemm16(sC, sE, ry, mx, acc);
  }
  float c2[8], eq[8];
  *(float4*)&c2[0] = *(const float4*)&cur2[r0 + ry];
  *(float4*)&c2[4] = *(const float4*)&cur2[r0 + ry + 4];
  *(float4*)&eq[0] = *(const float4*)&esq[m0 + mx];
  *(float4*)&eq[4] = *(const float4*)&esq[m0 + mx + 4];
  #pragma unroll
  for (int rr = 0; rr < 8; ++rr) {
    float o[8];
    #pragma unroll
    for (int mm = 0; mm < 8; ++mm) {
      const float dist = c2[rr] + eq[mm] - 2.0f * acc[rr][mm];
      o[mm] = -dist;
    }
    float* dst = dm + (size_t)(r0 + ry + rr) * M_ + m0 + mx;
    *(float4*)dst = *(float4*)&o[0];
    *(float4*)(dst + 4) = *(float4*)&o[4];
  }
}

// ---------------- per-row softmax-sum / argmax / gumbel argmax (wave per 16 rows) ----------------
__global__ __launch_bounds__(256) void k_soft(const float* __restrict__ dm,
                                              const float* __restrict__ gu,
                                              float* __restrict__ soft4,
                                              unsigned* __restrict__ hist,
                                              int* __restrict__ idxi,
                                              float* __restrict__ idxf) {
  const int tid = threadIdx.x;
  const int lane = tid & 63, w = tid >> 6;
  __shared__ float accS[1024];
  __shared__ unsigned histS[1024];
  for (int j = tid; j < 1024; j += 256) { accS[j] = 0.f; histS[j] = 0u; }
  __syncthreads();
  float p[16] = {};
  const int rbase = (blockIdx.x << 6) + (w << 4);
  for (int rr = 0; rr < 16; ++rr) {
    const int r = rbase + rr;
    const float4* dr = (const float4*)(dm + ((size_t)r << 10));
    float v[16];   // slot s=4k+j -> m = 4*lane + 256*k + j (ascending per lane)
    #pragma unroll
    for (int k = 0; k < 4; ++k) {
      const float4 d = dr[lane + (k << 6)];
      v[k * 4 + 0] = d.x; v[k * 4 + 1] = d.y; v[k * 4 + 2] = d.z; v[k * 4 + 3] = d.w;
    }
    float mx = v[0];
    #pragma unroll
    for (int s = 1; s < 16; ++s) mx = fmaxf(mx, v[s]);
    #pragma unroll
    for (int m = 32; m; m >>= 1) mx = fmaxf(mx, __shfl_xor(mx, m, 64));
    float e[16]; float sum = 0.f;
    #pragma unroll
    for (int s = 0; s < 16; ++s) { e[s] = expf(v[s] - mx); sum += e[s]; }
    #pragma unroll
    for (int m = 32; m; m >>= 1) sum += __shfl_xor(sum, m, 64);
    const float inv = 1.0f / sum;
    #pragma unroll
    for (int s = 0; s < 16; ++s) p[s] = fmaf(e[s], inv, p[s]);
    // hard argmax (first occurrence)
    float bv = v[0]; int bi = (lane << 2);
    #pragma unroll
    for (int s = 1; s < 16; ++s) {
      const int m_ = (lane << 2) + ((s >> 2) << 8) + (s & 3);
      if (v[s] > bv) { bv = v[s]; bi = m_; }
    }
    #pragma unroll
    for (int m = 32; m; m >>= 1) {
      const float ov = __shfl_xor(bv, m, 64);
      const int oi = __shfl_xor(bi, m, 64);
      if (ov > bv || (ov == bv && oi < bi)) { bv = ov; bi = oi; }
    }
    if (lane == 0) atomicAdd(&histS[bi], 1u);
    // gumbel argmax of dm + g
    const float4* gr = (const float4*)(gu + ((size_t)r << 10));
    float z[16];
    #pragma unroll
    for (int k = 0; k < 4; ++k) {
      const float4 u = gr[lane + (k << 6)];
      const float uu[4] = {u.x, u.y, u.z, u.w};
      #pragma unroll
      for (int j = 0; j < 4; ++j) {
        const float uc = fminf(fmaxf(uu[j], 1e-10f), 1.0f - 1e-7f);
        z[k * 4 + j] = v[k * 4 + j] - logf(-logf(uc));
      }
    }
    bv = z[0]; bi = (lane << 2);
    #pragma unroll
    for (int s = 1; s < 16; ++s) {
      const int m_ = (lane << 2) + ((s >> 2) << 8) + (s & 3);
      if (z[s] > bv) { bv = z[s]; bi = m_; }
    }
    #pragma unroll
    for (int m = 32; m; m >>= 1) {
      const float ov = __shfl_xor(bv, m, 64);
      const int oi = __shfl_xor(bi, m, 64);
      if (ov > bv || (ov == bv && oi < bi)) { bv = ov; bi = oi; }
    }
    if (lane == 0) { idxi[r] = bi; idxf[r] = (float)bi; }
  }
  #pragma unroll
  for (int s = 0; s < 16; ++s)
    atomicAdd(&accS[(lane << 2) + ((s >> 2) << 8) + (s & 3)], p[s]);
  __syncthreads();
  const int rep = (blockIdx.x & 3) << 10;
  for (int j = tid; j < 1024; j += 256) {
    atomicAdd(&soft4[rep + j], accS[j]);
    const unsigned h = histS[j];
    if (h) atomicAdd(&hist[j], h);
  }
}

// ---------------- perplexities ----------------
__global__ __launch_bounds__(256) void k_perp(const float* __restrict__ soft4,
                                              const unsigned* __restrict__ hist,
                                              float* __restrict__ out2) {
  const int tid = threadIdx.x;
  float cp = 0.f, pp = 0.f;
  for (int m = tid; m < 1024; m += 256) {
    const float hp = (float)hist[m] * (1.0f / 32768.0f);
    cp += hp * log2f(hp + 1e-10f);
    const float q = (soft4[m] + soft4[1024 + m] + soft4[2048 + m] + soft4[3072 + m]) * (1.0f / 32768.0f);
    pp += q * log2f(q + 1e-10f);
  }
  #pragma unroll
  for (int off = 32; off; off >>= 1) {
    cp += __shfl_down(cp, off, 64);
    pp += __shfl_down(pp, off, 64);
  }
  __shared__ float rc[4], rp[4];
  const int lane = tid & 63, wv = tid >> 6;
  if (lane == 0) { rc[wv] = cp; rp[wv] = pp; }
  __syncthreads();
  if (tid == 0) {
    out2[0] = -((rc[0] + rc[1]) + (rc[2] + rc[3]));
    out2[1] = -((rp[0] + rp[1]) + (rp[2] + rp[3]));
  }
}

// ---------------- fuse2: out[row][o] = prelu(P[idx_row][o] + sum_c w2b[o][c]*ctxo[c][t]) ----------------
__global__ __launch_bounds__(256) void k_fuse2(const float* __restrict__ ctxo,
                                               const float* __restrict__ w2T,
                                               const float* __restrict__ P,
                                               const int* __restrict__ idxi,
                                               const float* __restrict__ a2,
                                               float* __restrict__ outq) {
  const int bk = blockIdx.x;
  const int b = bk >> 5;
  const int t0 = (bk & 31) << 7;
  const int o0 = blockIdx.y << 7;
  const int tid = threadIdx.x;
  const int tx = tid & 15, ty = tid >> 4;
  const int ay = ty << 3, ox = tx << 3;   // t-frag (A), o-frag (B)
  __shared__ float smem[4096];
  __shared__ int idxS[128];
  float* sX = smem;          // [c][t]
  float* sW = smem + 2048;   // [c][o]
  if (tid < 128) idxS[tid] = idxi[(size_t)b * T_ + t0 + tid];
  float acc[8][8] = {};      // [tt][oo]
  for (int cc = 0; cc < 256; cc += 16) {
    __syncthreads();
    stage16x128(sX, ctxo + ((size_t)b * D_ + cc) * T_ + t0, T_, tid);
    stage16x128(sW, w2T + (size_t)(256 + cc) * 256 + o0, 256, tid);
    __syncthreads();
    gemm16(sX, sW, ay, ox, acc);
  }
  const float alpha = a2[0];
  #pragma unroll
  for (int tt = 0; tt < 8; ++tt) {
    const int id = idxS[ay + tt];
    const float* pr = P + (size_t)id * 256 + o0 + ox;
    float4 p0 = *(const float4*)pr;
    float4 p1 = *(const float4*)(pr + 4);
    const float pv[8] = {p0.x, p0.y, p0.z, p0.w, p1.x, p1.y, p1.z, p1.w};
    float o[8];
    #pragma unroll
    for (int oo = 0; oo < 8; ++oo) {
      float v = acc[tt][oo] + pv[oo];
      o[oo] = (v >= 0.f) ? v : alpha * v;
    }
    float* dst = outq + ((size_t)b * T_ + t0 + ay + tt) * D_ + o0 + ox;
    *(float4*)dst = *(float4*)&o[0];
    *(float4*)(dst + 4) = *(float4*)&o[4];
  }
}

extern "C" void kernel_launch(void* const* d_in, const int* in_sizes, int n_in,
                              void* d_out, int out_size, void* d_ws, size_t ws_size,
                              hipStream_t stream) {
  (void)in_sizes; (void)n_in; (void)out_size; (void)ws_size;
  const float* x     = (const float*)d_in[0];
  const float* noise = (const float*)d_in[1];
  const float* gu    = (const float*)d_in[2];
  const int*   epo   = (const int*)d_in[3];
  const float* emb   = (const float*)d_in[4];
  const float* wctx  = (const float*)d_in[5];
  const float* wf1   = (const float*)d_in[6];
  const float* a1    = (const float*)d_in[7];
  const float* wf2   = (const float*)d_in[8];
  const float* a2    = (const float*)d_in[9];

  float* ws   = (float*)d_ws;
  float* dm   = ws + OFF_DM;
  float* xT   = ws + OFF_XT;
  float* ctxn = ws + OFF_CTXN;
  float* curT = ws + OFF_CURT;
  float* ctxo = ws + OFF_CTXO;
  float* cur2 = ws + OFF_CUR2;
  float* soft = ws + OFF_SOFT;
  unsigned* hist = (unsigned*)(ws + OFF_HIST);
  float* sumsq = ws + OFF_SUMSQ;
  float* esq  = ws + OFF_ESQ;
  int*   idxi = (int*)(ws + OFF_IDX);
  float* ET   = ws + OFF_ET;
  float* W1T  = ws + OFF_W1T;
  float* W2T  = ws + OFF_W2T;
  float* WCT  = ws + OFF_WCT;
  float* P    = ws + OFF_P;

  float* outq = (float*)d_out;
  float* scal = outq + (size_t)NROW_ * D_;      // [cp, pp]
  float* idxf = scal + 2;                        // 32768 indices as float

  // zero CUR2 + SOFT(4 reps) + HIST + SUMSQ (contiguous)
  hipMemsetAsync(ws + OFF_CUR2, 0, (NROW_ + 4096 + 1024 + 16) * sizeof(float), stream);

  k_transpose<<<dim3(8, 32), 256, 0, stream>>>(emb, ET, 1024, 256);
  k_transpose<<<dim3(16, 8), 256, 0, stream>>>(wf1, W1T, 256, 512);
  k_transpose<<<dim3(16, 8), 256, 0, stream>>>(wf2, W2T, 256, 512);
  k_transpose<<<dim3(56, 8), 256, 0, stream>>>(wctx, WCT, 256, 1792);
  k_rownorm<<<M_ / 4, 256, 0, stream>>>(emb, esq);
  k_sumsq<<<512, 256, 0, stream>>>(x, sumsq);
  k_noisy<<<dim3(129, 8, 8), 256, 0, stream>>>(x, noise, epo, sumsq, ctxn, xT);
  k_conv<<<dim3(32, 2, 8), 256, 0, stream>>>(WCT, ctxn, ctxo);
  k_fuse1<<<dim3(256, 2), 256, 0, stream>>>(xT, ctxo, W1T, a1, curT, cur2);
  k_pmm<<<dim3(8, 2), 256, 0, stream>>>(ET, W2T, P);
  k_dist<<<dim3(256, 8), 256, 0, stream>>>(curT, ET, cur2, esq, dm);
  k_soft<<<512, 256, 0, stream>>>(dm, gu, soft, hist, idxi, idxf);
  k_perp<<<1, 256, 0, stream>>>(soft, hist, scal);
  k_fuse2<<<dim3(256, 2), 256, 0, stream>>>(ctxo, W2T, P, idxi, a2, outq);
}

// Round 3
// 1125.251 us; speedup vs baseline: 1.5158x; 1.0056x over previous
//
#include <hip/hip_runtime.h>
#include <cmath>

#define B_    8
#define T_    4096
#define D_    256
#define M_    1024
#define L_    4102     // T-1+CTX
#define LP_   4104     // padded stride for ctxn rows
#define CTX_  7
#define NROW_ 32768    // B*T

// ---------------- workspace layout (float elements) ----------------
// DM (33.5M) overlaps XT (first 8.39M, dead after fuse1) and CTXOB
// (second 8.39M, dead after addctx). CURT overlaps CTXN (dead after conv).
constexpr size_t OFF_DM    = 0;                                  // 33,554,432
constexpr size_t OFF_XT    = 0;                                  // 8,388,608
constexpr size_t OFF_CTXOB = 8388608;                            // 8,388,608
constexpr size_t OFF_CTXN  = 33554432;                           // 8*256*4104 = 8,404,992
constexpr size_t OFF_CURT  = 33554432;                           // [256][32768]
constexpr size_t OFF_CTXO  = OFF_CTXN + (size_t)B_ * D_ * LP_;   // 41,959,424
constexpr size_t OFF_CUR2  = OFF_CTXO + (size_t)B_ * D_ * T_;    // 50,348,032
constexpr size_t OFF_SOFT  = OFF_CUR2 + NROW_;                   // 4096 (4 replicas)
constexpr size_t OFF_HIST  = OFF_SOFT + 4096;
constexpr size_t OFF_SUMSQ = OFF_HIST + 1024;                    // 16
constexpr size_t OFF_ESQ   = OFF_SUMSQ + 16;
constexpr size_t OFF_IDX   = OFF_ESQ + 1024;
constexpr size_t OFF_ET    = OFF_IDX + NROW_;                    // [256][1024]
constexpr size_t OFF_W1T   = OFF_ET + 262144;                    // [512][256]
constexpr size_t OFF_W2T   = OFF_W1T + 131072;
constexpr size_t OFF_WCT   = OFF_W2T + 131072;                   // [1792][256]
constexpr size_t OFF_P     = OFF_WCT + 458752;                   // [1024][256]
// end ~51.66M floats = ~207 MB

// ---------------- prep: 4 transposes + emb rownorm + x sumsq, one launch ----------------
__global__ __launch_bounds__(256) void k_prep(const float* __restrict__ emb,
                                              const float* __restrict__ wf1,
                                              const float* __restrict__ wf2,
                                              const float* __restrict__ wctx,
                                              const float* __restrict__ x,
                                              float* __restrict__ ET,
                                              float* __restrict__ W1T,
                                              float* __restrict__ W2T,
                                              float* __restrict__ WCT,
                                              float* __restrict__ esq,
                                              float* __restrict__ sumsq) {
  const int id = blockIdx.x;
  if (id < 960) {
    __shared__ float tile[32][33];
    const int tx = threadIdx.x & 31, ty = threadIdx.x >> 5;
    const float* src; float* dst; int R, C, c0, r0;
    if (id < 256)      { src = emb;  dst = ET;  R = 1024; C = 256;  c0 = (id & 7) << 5;  r0 = (id >> 3) << 5; }
    else if (id < 384) { const int r = id - 256; src = wf1; dst = W1T; R = 256; C = 512; c0 = (r & 15) << 5; r0 = (r >> 4) << 5; }
    else if (id < 512) { const int r = id - 384; src = wf2; dst = W2T; R = 256; C = 512; c0 = (r & 15) << 5; r0 = (r >> 4) << 5; }
    else               { const int r = id - 512; src = wctx; dst = WCT; R = 256; C = 1792; c0 = (r % 56) << 5; r0 = (r / 56) << 5; }
    for (int rr = ty; rr < 32; rr += 8) {
      const int rI = r0 + rr, cI = c0 + tx;
      tile[rr][tx] = (rI < R && cI < C) ? src[(size_t)rI * C + cI] : 0.f;
    }
    __syncthreads();
    for (int rr = ty; rr < 32; rr += 8) {
      const int cI = c0 + rr, rI = r0 + tx;
      if (cI < C && rI < R) dst[(size_t)cI * R + rI] = tile[tx][rr];
    }
  } else if (id < 1216) {
    const int row = ((id - 960) << 2) + (threadIdx.x >> 6);
    const int lane = threadIdx.x & 63;
    const float4 v = ((const float4*)emb)[((size_t)row << 6) + lane];
    float s = v.x * v.x + v.y * v.y + v.z * v.z + v.w * v.w;
    #pragma unroll
    for (int off = 32; off; off >>= 1) s += __shfl_down(s, off, 64);
    if (lane == 0) esq[row] = s;
  } else {
    const int chunk = id - 1216;           // 0..511
    const int b = chunk >> 6, sub = chunk & 63;
    const float4* xb = (const float4*)(x + (size_t)b * T_ * D_);
    const int N4 = (T_ - 1) * D_ / 4;
    float s = 0.f;
    for (int j = sub * 256 + threadIdx.x; j < N4; j += 64 * 256) {
      float4 v = xb[j];
      s += v.x * v.x + v.y * v.y + v.z * v.z + v.w * v.w;
    }
    #pragma unroll
    for (int off = 32; off; off >>= 1) s += __shfl_down(s, off, 64);
    __shared__ float red[4];
    const int lane = threadIdx.x & 63, wv = threadIdx.x >> 6;
    if (lane == 0) red[wv] = s;
    __syncthreads();
    if (threadIdx.x == 0) atomicAdd(&sumsq[b], (red[0] + red[1]) + (red[2] + red[3]));
  }
}

// ---------------- noisy ctx input [b][i][tau] (stride LP_) + xT [b][i][t] ----------------
__global__ __launch_bounds__(256) void k_noisy(const float* __restrict__ x,
                                               const float* __restrict__ noise,
                                               const int* __restrict__ epo,
                                               const float* __restrict__ sumsq,
                                               float* __restrict__ ctxn,
                                               float* __restrict__ xT) {
  const int b = blockIdx.z;
  const int i0 = blockIdx.y << 5;
  const int tau0 = blockIdx.x << 5;
  const int tx = threadIdx.x & 31, ty = threadIdx.x >> 5;
  __shared__ float xt[32][33];
  const int tr0 = tau0 - CTX_;
  for (int r = ty; r < 32; r += 8) {
    const int t = tr0 + r;
    xt[r][tx] = (t >= 0 && t < T_) ? x[((size_t)b * T_ + t) * D_ + i0 + tx] : 0.f;
  }
  __syncthreads();
  const float scale = sqrtf(sumsq[b] * (1.0f / (256.0f * 4102.0f)));
  const float coef = 0.5f * powf(0.5f, (float)epo[0] * 0.1f) * scale;
  for (int r = ty; r < 32; r += 8) {
    const int i = i0 + r;
    const int tau = tau0 + tx;
    const float xv = xt[tx][r];
    if (tau < L_) {
      float v = coef * noise[((size_t)b * D_ + i) * L_ + tau];
      if (tau >= CTX_) v += xv;
      ctxn[((size_t)b * D_ + i) * LP_ + tau] = v;
    }
    if (tau >= CTX_ && tau < T_ + CTX_) {
      xT[((size_t)b * D_ + i) * T_ + (tau - CTX_)] = xv;
    }
  }
}

// ---------------- shared GEMM helpers ----------------
__device__ __forceinline__ void stage16x128(float* __restrict__ dst,
                                            const float* __restrict__ src,
                                            const int gstride, const int tid) {
  #pragma unroll
  for (int p = 0; p < 2; ++p) {
    const int q = p * 256 + tid;
    const int r = q >> 5, c = (q & 31) << 2;
    *(float4*)&dst[(r << 7) + c] = *(const float4*)&src[(size_t)r * gstride + c];
  }
}

// A-frag: 8 contiguous rows at ay (broadcast per 16 lanes -> conflict-free).
// B-frag: 4+4 split at bx4 and bx4+64 (lane stride 4 floats -> 2-way, free).
// acc[i][j]: j<4 -> col bx4+j ; j>=4 -> col bx4+64+(j-4)
__device__ __forceinline__ void gemm16s(const float* __restrict__ sA,
                                        const float* __restrict__ sB,
                                        const int ay, const int bx4,
                                        float acc[8][8]) {
  #pragma unroll 4
  for (int c = 0; c < 16; ++c) {
    const float4 a0 = *(const float4*)&sA[(c << 7) + ay];
    const float4 a1 = *(const float4*)&sA[(c << 7) + ay + 4];
    const float4 b0 = *(const float4*)&sB[(c << 7) + bx4];
    const float4 b1 = *(const float4*)&sB[(c << 7) + bx4 + 64];
    const float av[8] = {a0.x, a0.y, a0.z, a0.w, a1.x, a1.y, a1.z, a1.w};
    const float bv[8] = {b0.x, b0.y, b0.z, b0.w, b1.x, b1.y, b1.z, b1.w};
    #pragma unroll
    for (int i = 0; i < 8; ++i)
      #pragma unroll
      for (int j = 0; j < 8; ++j)
        acc[i][j] = fmaf(av[i], bv[j], acc[i][j]);
  }
}

// ---------------- conv (K-split): ctxoPart[b][o][t] = sum_{i in half,h} W*in ----------------
__global__ __launch_bounds__(256) void k_conv(const float* __restrict__ wct,
                                              const float* __restrict__ ctxn,
                                              float* __restrict__ ctxoA,
                                              float* __restrict__ ctxoB) {
  const int t0 = blockIdx.x << 7;
  const int o0 = blockIdx.y << 7;
  const int b  = blockIdx.z >> 1;
  const int s  = blockIdx.z & 1;
  const int tid = threadIdx.x;
  const int tx = tid & 15, ty = tid >> 4;
  const int bx4 = tx << 2, ay = ty << 3;   // t-frag (split 4+4), o-frag
  __shared__ float wS[56 * 128];           // [i*7+h][o]
  __shared__ float inS[8 * 136];           // [i][tau]
  float acc[8][8] = {};                    // [oo][tt] tt<4 -> bx4+tt, tt>=4 -> bx4+64+tt-4
  const int icBase = s << 4;
  for (int icr = 0; icr < 16; ++icr) {
    const int ic = icBase + icr;
    __syncthreads();
    #pragma unroll
    for (int p = 0; p < 7; ++p) {
      const int q = p * 256 + tid;
      const int r = q >> 5, c = (q & 31) << 2;
      *(float4*)&wS[(r << 7) + c] = *(const float4*)&wct[(size_t)(ic * 56 + r) * 256 + o0 + c];
    }
    {
      const int r = tid / 34, c = (tid % 34) << 2;
      if (tid < 272)
        *(float4*)&inS[r * 136 + c] = *(const float4*)&ctxn[((size_t)b * D_ + ic * 8 + r) * LP_ + t0 + c];
      if (tid < 16) {
        const int q2 = 256 + tid;
        const int r2 = q2 / 34, c2 = (q2 % 34) << 2;
        *(float4*)&inS[r2 * 136 + c2] = *(const float4*)&ctxn[((size_t)b * D_ + ic * 8 + r2) * LP_ + t0 + c2];
      }
    }
    __syncthreads();
    #pragma unroll 1
    for (int i = 0; i < 8; ++i) {
      float iv0[12], iv1[12];
      #pragma unroll
      for (int q = 0; q < 3; ++q) {
        *(float4*)&iv0[q << 2] = *(const float4*)&inS[i * 136 + bx4 + (q << 2)];
        *(float4*)&iv1[q << 2] = *(const float4*)&inS[i * 136 + bx4 + 64 + (q << 2)];
      }
      #pragma unroll
      for (int h = 0; h < 7; ++h) {
        float wv[8];
        *(float4*)&wv[0] = *(const float4*)&wS[(i * 7 + h) * 128 + ay];
        *(float4*)&wv[4] = *(const float4*)&wS[(i * 7 + h) * 128 + ay + 4];
        #pragma unroll
        for (int oo = 0; oo < 8; ++oo)
          #pragma unroll
          for (int tt = 0; tt < 4; ++tt) {
            acc[oo][tt]     = fmaf(wv[oo], iv0[h + tt], acc[oo][tt]);
            acc[oo][tt + 4] = fmaf(wv[oo], iv1[h + tt], acc[oo][tt + 4]);
          }
      }
    }
  }
  float* out = s ? ctxoB : ctxoA;
  #pragma unroll
  for (int oo = 0; oo < 8; ++oo) {
    const float4 v0 = {acc[oo][0], acc[oo][1], acc[oo][2], acc[oo][3]};
    const float4 v1 = {acc[oo][4], acc[oo][5], acc[oo][6], acc[oo][7]};
    float* dst = out + ((size_t)b * D_ + o0 + ay + oo) * T_ + t0;
    *(float4*)(dst + bx4) = v0;
    *(float4*)(dst + bx4 + 64) = v1;
  }
}

// ---------------- ctxoA += ctxoB ----------------
__global__ __launch_bounds__(256) void k_addctx(float* __restrict__ a,
                                                const float* __restrict__ b) {
  const size_t i = (size_t)blockIdx.x * 256 + threadIdx.x;
  float4* A = (float4*)a; const float4* Bv = (const float4*)b;
  #pragma unroll
  for (int k = 0; k < 4; ++k) {
    const size_t j = i + (size_t)k * 524288;
    float4 va = A[j]; const float4 vb = Bv[j];
    va.x += vb.x; va.y += vb.y; va.z += vb.z; va.w += vb.w;
    A[j] = va;
  }
}

// ---------------- fuse1 -> curT[o][row] + cur2[row] ----------------
__global__ __launch_bounds__(256) void k_fuse1(const float* __restrict__ xT,
                                               const float* __restrict__ ctxo,
                                               const float* __restrict__ w1T,
                                               const float* __restrict__ a1,
                                               float* __restrict__ curT,
                                               float* __restrict__ cur2) {
  const int bk = blockIdx.x;
  const int b = bk >> 5;
  const int t0 = (bk & 31) << 7;
  const int o0 = blockIdx.y << 7;
  const int tid = threadIdx.x;
  const int tx = tid & 15, ty = tid >> 4;
  const int ox = ty << 3, tp4 = tx << 2;   // o-frag (A), t-frag (B split)
  __shared__ float smem[4096];
  float* sW = smem;          // [c][o]
  float* sX = smem + 2048;   // [c][t]
  float acc[8][8] = {};      // [oo][tj]
  for (int cc = 0; cc < 512; cc += 16) {
    __syncthreads();
    stage16x128(sW, w1T + (size_t)cc * 256 + o0, 256, tid);
    const float* xsrc = (cc < 256)
        ? xT + ((size_t)b * D_ + cc) * T_ + t0
        : ctxo + ((size_t)b * D_ + (cc - 256)) * T_ + t0;
    stage16x128(sX, xsrc, T_, tid);
    __syncthreads();
    gemm16s(sW, sX, ox, tp4, acc);
  }
  const float alpha = a1[0];
  const size_t row0 = (size_t)b * T_ + t0;
  float part[8] = {};
  #pragma unroll
  for (int oo = 0; oo < 8; ++oo) {
    #pragma unroll
    for (int j = 0; j < 8; ++j) {
      float v = acc[oo][j];
      v = (v >= 0.f) ? v : alpha * v;
      acc[oo][j] = v;
      part[j] = fmaf(v, v, part[j]);
    }
    const float4 v0 = {acc[oo][0], acc[oo][1], acc[oo][2], acc[oo][3]};
    const float4 v1 = {acc[oo][4], acc[oo][5], acc[oo][6], acc[oo][7]};
    float* dst = curT + (size_t)(o0 + ox + oo) * NROW_ + row0;
    *(float4*)(dst + tp4) = v0;
    *(float4*)(dst + tp4 + 64) = v1;
  }
  __syncthreads();
  float* red = smem;   // [128][17]
  #pragma unroll
  for (int j = 0; j < 4; ++j) {
    red[(tp4 + j) * 17 + ty] = part[j];
    red[(tp4 + 64 + j) * 17 + ty] = part[4 + j];
  }
  __syncthreads();
  if (tid < 128) {
    float s = 0.f;
    #pragma unroll
    for (int k = 0; k < 16; ++k) s += red[tid * 17 + k];
    atomicAdd(&cur2[row0 + tid], s);
  }
}

// ---------------- P[m][o] = sum_c E[m][c] * wf2[o][c]  (c<256 half) ----------------
__global__ __launch_bounds__(256) void k_pmm(const float* __restrict__ ET,
                                             const float* __restrict__ w2T,
                                             float* __restrict__ P) {
  const int m0 = blockIdx.x << 7;
  const int o0 = blockIdx.y << 7;
  const int tid = threadIdx.x;
  const int tx = tid & 15, ty = tid >> 4;
  const int my = ty << 3, ox4 = tx << 2;
  __shared__ float smem[4096];
  float* sM = smem;
  float* sW = smem + 2048;
  float acc[8][8] = {};   // [mm][oj]
  for (int cc = 0; cc < 256; cc += 16) {
    __syncthreads();
    stage16x128(sM, ET + (size_t)cc * M_ + m0, M_, tid);
    stage16x128(sW, w2T + (size_t)cc * 256 + o0, 256, tid);
    __syncthreads();
    gemm16s(sM, sW, my, ox4, acc);
  }
  #pragma unroll
  for (int mm = 0; mm < 8; ++mm) {
    const float4 v0 = {acc[mm][0], acc[mm][1], acc[mm][2], acc[mm][3]};
    const float4 v1 = {acc[mm][4], acc[mm][5], acc[mm][6], acc[mm][7]};
    float* dst = P + (size_t)(m0 + my + mm) * 256 + o0;
    *(float4*)(dst + ox4) = v0;
    *(float4*)(dst + ox4 + 64) = v1;
  }
}

// ---------------- dist: dm[row][m] = -(c2 + e2 - 2*cur.e) ----------------
__global__ __launch_bounds__(256) void k_dist(const float* __restrict__ curT,
                                              const float* __restrict__ ET,
                                              const float* __restrict__ cur2,
                                              const float* __restrict__ esq,
                                              float* __restrict__ dm) {
  const int r0 = blockIdx.x << 7;
  const int m0 = blockIdx.y << 7;
  const int tid = threadIdx.x;
  const int tx = tid & 15, ty = tid >> 4;
  const int ry = ty << 3, mx4 = tx << 2;
  __shared__ float smem[4096];
  float* sC = smem;
  float* sE = smem + 2048;
  float acc[8][8] = {};   // [rr][mj]
  for (int cc = 0; cc < 256; cc += 16) {
    __syncthreads();
    stage16x128(sC, curT + (size_t)cc * NROW_ + r0, NROW_, tid);
    stage16x128(sE, ET + (size_t)cc * M_ + m0, M_, tid);
    __syncthreads();
    gemm16s(sC, sE, ry, mx4, acc);
  }
  float c2[8], eq0[4], eq1[4];
  *(float4*)&c2[0] = *(const float4*)&cur2[r0 + ry];
  *(float4*)&c2[4] = *(const float4*)&cur2[r0 + ry + 4];
  *(float4*)&eq0[0] = *(const float4*)&esq[m0 + mx4];
  *(float4*)&eq1[0] = *(const float4*)&esq[m0 + mx4 + 64];
  #pragma unroll
  for (int rr = 0; rr < 8; ++rr) {
    float o0v[4], o1v[4];
    #pragma unroll
    for (int j = 0; j < 4; ++j) {
      o0v[j] = -(c2[rr] + eq0[j] - 2.0f * acc[rr][j]);
      o1v[j] = -(c2[rr] + eq1[j] - 2.0f * acc[rr][j + 4]);
    }
    float* dst = dm + (size_t)(r0 + ry + rr) * M_ + m0;
    *(float4*)(dst + mx4) = *(float4*)&o0v[0];
    *(float4*)(dst + mx4 + 64) = *(float4*)&o1v[0];
  }
}

// ---------------- per-row softmax-sum / argmax / gumbel argmax (wave per 16 rows) ----------------
__global__ __launch_bounds__(256) void k_soft(const float* __restrict__ dm,
                                              const float* __restrict__ gu,
                                              float* __restrict__ soft4,
                                              unsigned* __restrict__ hist,
                                              int* __restrict__ idxi,
                                              float* __restrict__ idxf) {
  const int tid = threadIdx.x;
  const int lane = tid & 63, w = tid >> 6;
  __shared__ float accS[1024];
  __shared__ unsigned histS[1024];
  for (int j = tid; j < 1024; j += 256) { accS[j] = 0.f; histS[j] = 0u; }
  __syncthreads();
  float p[16] = {};
  const int rbase = (blockIdx.x << 6) + (w << 4);
  for (int rr = 0; rr < 16; ++rr) {
    const int r = rbase + rr;
    const float4* dr = (const float4*)(dm + ((size_t)r << 10));
    float v[16];
    #pragma unroll
    for (int k = 0; k < 4; ++k) {
      const float4 d = dr[lane + (k << 6)];
      v[k * 4 + 0] = d.x; v[k * 4 + 1] = d.y; v[k * 4 + 2] = d.z; v[k * 4 + 3] = d.w;
    }
    float mx = v[0];
    #pragma unroll
    for (int s = 1; s < 16; ++s) mx = fmaxf(mx, v[s]);
    #pragma unroll
    for (int m = 32; m; m >>= 1) mx = fmaxf(mx, __shfl_xor(mx, m, 64));
    float e[16]; float sum = 0.f;
    #pragma unroll
    for (int s = 0; s < 16; ++s) { e[s] = expf(v[s] - mx); sum += e[s]; }
    #pragma unroll
    for (int m = 32; m; m >>= 1) sum += __shfl_xor(sum, m, 64);
    const float inv = 1.0f / sum;
    #pragma unroll
    for (int s = 0; s < 16; ++s) p[s] = fmaf(e[s], inv, p[s]);
    float bv = v[0]; int bi = (lane << 2);
    #pragma unroll
    for (int s = 1; s < 16; ++s) {
      const int m_ = (lane << 2) + ((s >> 2) << 8) + (s & 3);
      if (v[s] > bv) { bv = v[s]; bi = m_; }
    }
    #pragma unroll
    for (int m = 32; m; m >>= 1) {
      const float ov = __shfl_xor(bv, m, 64);
      const int oi = __shfl_xor(bi, m, 64);
      if (ov > bv || (ov == bv && oi < bi)) { bv = ov; bi = oi; }
    }
    if (lane == 0) atomicAdd(&histS[bi], 1u);
    const float4* gr = (const float4*)(gu + ((size_t)r << 10));
    float z[16];
    #pragma unroll
    for (int k = 0; k < 4; ++k) {
      const float4 u = gr[lane + (k << 6)];
      const float uu[4] = {u.x, u.y, u.z, u.w};
      #pragma unroll
      for (int j = 0; j < 4; ++j) {
        const float uc = fminf(fmaxf(uu[j], 1e-10f), 1.0f - 1e-7f);
        z[k * 4 + j] = v[k * 4 + j] - logf(-logf(uc));
      }
    }
    bv = z[0]; bi = (lane << 2);
    #pragma unroll
    for (int s = 1; s < 16; ++s) {
      const int m_ = (lane << 2) + ((s >> 2) << 8) + (s & 3);
      if (z[s] > bv) { bv = z[s]; bi = m_; }
    }
    #pragma unroll
    for (int m = 32; m; m >>= 1) {
      const float ov = __shfl_xor(bv, m, 64);
      const int oi = __shfl_xor(bi, m, 64);
      if (ov > bv || (ov == bv && oi < bi)) { bv = ov; bi = oi; }
    }
    if (lane == 0) { idxi[r] = bi; idxf[r] = (float)bi; }
  }
  #pragma unroll
  for (int s = 0; s < 16; ++s)
    atomicAdd(&accS[(lane << 2) + ((s >> 2) << 8) + (s & 3)], p[s]);
  __syncthreads();
  const int rep = (blockIdx.x & 3) << 10;
  for (int j = tid; j < 1024; j += 256) {
    atomicAdd(&soft4[rep + j], accS[j]);
    const unsigned h = histS[j];
    if (h) atomicAdd(&hist[j], h);
  }
}

// ---------------- perplexities ----------------
__global__ __launch_bounds__(256) void k_perp(const float* __restrict__ soft4,
                                              const unsigned* __restrict__ hist,
                                              float* __restrict__ out2) {
  const int tid = threadIdx.x;
  float cp = 0.f, pp = 0.f;
  for (int m = tid; m < 1024; m += 256) {
    const float hp = (float)hist[m] * (1.0f / 32768.0f);
    cp += hp * log2f(hp + 1e-10f);
    const float q = (soft4[m] + soft4[1024 + m] + soft4[2048 + m] + soft4[3072 + m]) * (1.0f / 32768.0f);
    pp += q * log2f(q + 1e-10f);
  }
  #pragma unroll
  for (int off = 32; off; off >>= 1) {
    cp += __shfl_down(cp, off, 64);
    pp += __shfl_down(pp, off, 64);
  }
  __shared__ float rc[4], rp[4];
  const int lane = tid & 63, wv = tid >> 6;
  if (lane == 0) { rc[wv] = cp; rp[wv] = pp; }
  __syncthreads();
  if (tid == 0) {
    out2[0] = -((rc[0] + rc[1]) + (rc[2] + rc[3]));
    out2[1] = -((rp[0] + rp[1]) + (rp[2] + rp[3]));
  }
}

// ---------------- fuse2: out[row][o] = prelu(P[idx_row][o] + w2b @ ctxo) ----------------
__global__ __launch_bounds__(256) void k_fuse2(const float* __restrict__ ctxo,
                                               const float* __restrict__ w2T,
                                               const float* __restrict__ P,
                                               const int* __restrict__ idxi,
                                               const float* __restrict__ a2,
                                               float* __restrict__ outq) {
  const int bk = blockIdx.x;
  const int b = bk >> 5;
  const int t0 = (bk & 31) << 7;
  const int o0 = blockIdx.y << 7;
  const int tid = threadIdx.x;
  const int tx = tid & 15, ty = tid >> 4;
  const int ay = ty << 3, ox4 = tx << 2;   // t-frag (A), o-frag (B split)
  __shared__ float smem[4096];
  __shared__ int idxS[128];
  float* sX = smem;          // [c][t]
  float* sW = smem + 2048;   // [c][o]
  if (tid < 128) idxS[tid] = idxi[(size_t)b * T_ + t0 + tid];
  float acc[8][8] = {};      // [tt][oj]
  for (int cc = 0; cc < 256; cc += 16) {
    __syncthreads();
    stage16x128(sX, ctxo + ((size_t)b * D_ + cc) * T_ + t0, T_, tid);
    stage16x128(sW, w2T + (size_t)(256 + cc) * 256 + o0, 256, tid);
    __syncthreads();
    gemm16s(sX, sW, ay, ox4, acc);
  }
  const float alpha = a2[0];
  #pragma unroll
  for (int tt = 0; tt < 8; ++tt) {
    const int id = idxS[ay + tt];
    const float* pr = P + (size_t)id * 256 + o0;
    const float4 p0 = *(const float4*)(pr + ox4);
    const float4 p1 = *(const float4*)(pr + ox4 + 64);
    const float pv[8] = {p0.x, p0.y, p0.z, p0.w, p1.x, p1.y, p1.z, p1.w};
    float o[8];
    #pragma unroll
    for (int oo = 0; oo < 8; ++oo) {
      const float v = acc[tt][oo] + pv[oo];
      o[oo] = (v >= 0.f) ? v : alpha * v;
    }
    float* dst = outq + ((size_t)b * T_ + t0 + ay + tt) * D_ + o0;
    *(float4*)(dst + ox4) = *(float4*)&o[0];
    *(float4*)(dst + ox4 + 64) = *(float4*)&o[4];
  }
}

extern "C" void kernel_launch(void* const* d_in, const int* in_sizes, int n_in,
                              void* d_out, int out_size, void* d_ws, size_t ws_size,
                              hipStream_t stream) {
  (void)in_sizes; (void)n_in; (void)out_size; (void)ws_size;
  const float* x     = (const float*)d_in[0];
  const float* noise = (const float*)d_in[1];
  const float* gu    = (const float*)d_in[2];
  const int*   epo   = (const int*)d_in[3];
  const float* emb   = (const float*)d_in[4];
  const float* wctx  = (const float*)d_in[5];
  const float* wf1   = (const float*)d_in[6];
  const float* a1    = (const float*)d_in[7];
  const float* wf2   = (const float*)d_in[8];
  const float* a2    = (const float*)d_in[9];

  float* ws    = (float*)d_ws;
  float* dm    = ws + OFF_DM;
  float* xT    = ws + OFF_XT;
  float* ctxoB = ws + OFF_CTXOB;
  float* ctxn  = ws + OFF_CTXN;
  float* curT  = ws + OFF_CURT;
  float* ctxo  = ws + OFF_CTXO;
  float* cur2  = ws + OFF_CUR2;
  float* soft  = ws + OFF_SOFT;
  unsigned* hist = (unsigned*)(ws + OFF_HIST);
  float* sumsq = ws + OFF_SUMSQ;
  float* esq   = ws + OFF_ESQ;
  int*   idxi  = (int*)(ws + OFF_IDX);
  float* ET    = ws + OFF_ET;
  float* W1T   = ws + OFF_W1T;
  float* W2T   = ws + OFF_W2T;
  float* WCT   = ws + OFF_WCT;
  float* P     = ws + OFF_P;

  float* outq = (float*)d_out;
  float* scal = outq + (size_t)NROW_ * D_;
  float* idxf = scal + 2;

  hipMemsetAsync(ws + OFF_CUR2, 0, (NROW_ + 4096 + 1024 + 16) * sizeof(float), stream);

  k_prep  <<<1728, 256, 0, stream>>>(emb, wf1, wf2, wctx, x, ET, W1T, W2T, WCT, esq, sumsq);
  k_noisy <<<dim3(129, 8, 8), 256, 0, stream>>>(x, noise, epo, sumsq, ctxn, xT);
  k_conv  <<<dim3(32, 2, 16), 256, 0, stream>>>(WCT, ctxn, ctxo, ctxoB);
  k_addctx<<<2048, 256, 0, stream>>>(ctxo, ctxoB);
  k_fuse1 <<<dim3(256, 2), 256, 0, stream>>>(xT, ctxo, W1T, a1, curT, cur2);
  k_pmm   <<<dim3(8, 2), 256, 0, stream>>>(ET, W2T, P);
  k_dist  <<<dim3(256, 8), 256, 0, stream>>>(curT, ET, cur2, esq, dm);
  k_soft  <<<512, 256, 0, stream>>>(dm, gu, soft, hist, idxi, idxf);
  k_perp  <<<1, 256, 0, stream>>>(soft, hist, scal);
  k_fuse2 <<<dim3(256, 2), 256, 0, stream>>>(ctxo, W2T, P, idxi, a2, outq);
}